// Round 3
// baseline (152.188 us; speedup 1.0000x reference)
//
#include <hip/hip_runtime.h>

// Ring-lattice sheaf Laplacian builder: N=50000 nodes, strides 1..16, d=4.
// d_out is FLOAT32, outputs concatenated flat (element offsets):
//   edge_index rows [0, 26.4M) | cols [26.4M, 52.8M)
//   weights         [52.8M, 79.2M)
//   saved_tril_maps [79.2M, 92.0M)
#define NN 50000
#define DG 16
#define EM 800000
#define OFF_COLS 26400000
#define OFF_W    52800000
#define OFF_TRIL 79200000
#define NIDX 6600000

typedef unsigned int  u32;
typedef long long ll64;

// ---- bf16 unpack (maps may be bf16-packed) ----
__device__ __forceinline__ void unpack8(uint4 v, float* f) {
    f[0] = __uint_as_float(v.x << 16); f[1] = __uint_as_float(v.x & 0xffff0000u);
    f[2] = __uint_as_float(v.y << 16); f[3] = __uint_as_float(v.y & 0xffff0000u);
    f[4] = __uint_as_float(v.z << 16); f[5] = __uint_as_float(v.z & 0xffff0000u);
    f[6] = __uint_as_float(v.w << 16); f[7] = __uint_as_float(v.w & 0xffff0000u);
}

// rank of node v within sorted({u} U {u +- s mod N, s=1..16}); 33 distinct values.
__device__ __forceinline__ int brank(int u, int v) {
    int a0 = u - DG; if (a0 < 0) a0 += NN;
    if (a0 <= NN - 33) return v - a0;          // contiguous [a0, a0+32]
    int k = a0 + 33 - NN;                      // wrapped values 0..k-1 sort first
    return (v < k) ? v : k + (v - a0);
}

// ---- dtype-flexible input loads ----
template<bool F32M>
__device__ __forceinline__ void load_map(const void* maps, size_t e, float* F) {
    if (F32M) {
        const float4* p = (const float4*)maps;
        float4 a = p[e*4+0], b = p[e*4+1], c = p[e*4+2], d = p[e*4+3];
        F[0]=a.x; F[1]=a.y; F[2]=a.z; F[3]=a.w;
        F[4]=b.x; F[5]=b.y; F[6]=b.z; F[7]=b.w;
        F[8]=c.x; F[9]=c.y; F[10]=c.z; F[11]=c.w;
        F[12]=d.x; F[13]=d.y; F[14]=d.z; F[15]=d.w;
    } else {
        const uint4* p = (const uint4*)maps;
        unpack8(p[e*2], F); unpack8(p[e*2+1], F + 8);
    }
}
template<bool I64>
__device__ __forceinline__ int ld_idx(const void* p, size_t i) {
    return I64 ? (int)((const ll64*)p)[i] : ((const int*)p)[i];
}

// ---- detection: flags[0] = indices are int64, flags[1] = maps are f32 ----
__global__ void k_detect(const u32* __restrict__ maps, const u32* __restrict__ li,
                         int* __restrict__ flags) {
    if (threadIdx.x == 0 && blockIdx.x == 0) {
        u32 odd = li[1] | li[3] | li[5] | li[7];     // int64 high words == 0
        flags[0] = (odd == 0u) ? 1 : 0;
        int sane = 0;
        for (int i = 0; i < 32; ++i) {               // low half as bf16: sane exponent?
            u32 ex = (maps[i] >> 7) & 0xFFu;
            if (ex >= 0x70u && ex <= 0x87u) ++sane;  // |x| in [2^-15, 2^8]
        }
        flags[1] = (sane < 16) ? 1 : 0;              // few sane => it's f32 bits
    }
}

// ---- Kernel 1: per tril edge, T = -L^T R -> tril + block(a,b) + block(b,a) ----
template<bool I64, bool F32M>
__device__ __forceinline__ void edges_body(int m, const void* maps, const void* li_,
                                           const void* ri_, const void* sr_,
                                           float* __restrict__ out) {
    int li = ld_idx<I64>(li_, m), ri = ld_idx<I64>(ri_, m);
    int a  = ld_idx<I64>(sr_, li), b = ld_idx<I64>(sr_, ri);   // a = src > dst = b
    float L[16], R[16];
    load_map<F32M>(maps, (size_t)li, L);
    load_map<F32M>(maps, (size_t)ri, R);
    float T[16];
#pragma unroll
    for (int x = 0; x < 4; ++x)
#pragma unroll
        for (int y = 0; y < 4; ++y)
            T[x*4+y] = -(L[x]*R[y] + L[4+x]*R[4+y] + L[8+x]*R[8+y] + L[12+x]*R[12+y]);
    // saved_tril_maps[m] (contiguous)
    float4* tp = (float4*)(out + OFF_TRIL) + (size_t)m * 4;
    tp[0] = make_float4(T[0],  T[1],  T[2],  T[3]);
    tp[1] = make_float4(T[4],  T[5],  T[6],  T[7]);
    tp[2] = make_float4(T[8],  T[9],  T[10], T[11]);
    tp[3] = make_float4(T[12], T[13], T[14], T[15]);
    // block (a,b): T[x][y] at global row a*4+x, col slot brank(a,b)*4+y
    int ra = brank(a, b);
    float* wa = out + OFF_W + (size_t)a*528 + ra*4;
#pragma unroll
    for (int x = 0; x < 4; ++x)
        *((float4*)(wa + x*132)) = make_float4(T[x*4], T[x*4+1], T[x*4+2], T[x*4+3]);
    // block (b,a) = T^T
    int rb = brank(b, a);
    float* wb = out + OFF_W + (size_t)b*528 + rb*4;
#pragma unroll
    for (int p = 0; p < 4; ++p)
        *((float4*)(wb + p*132)) = make_float4(T[p], T[4+p], T[8+p], T[12+p]);
}
__global__ void k_edges(const void* __restrict__ maps, const void* __restrict__ li_,
                        const void* __restrict__ ri_, const void* __restrict__ sr_,
                        float* __restrict__ out, const int* __restrict__ fl) {
    int m = blockIdx.x * 256 + threadIdx.x;
    if (m >= EM) return;
    int i6 = fl[0], f3 = fl[1];
    if (i6) { if (f3) edges_body<true ,true >(m, maps, li_, ri_, sr_, out);
              else    edges_body<true ,false>(m, maps, li_, ri_, sr_, out); }
    else    { if (f3) edges_body<false,true >(m, maps, li_, ri_, sr_, out);
              else    edges_body<false,false>(m, maps, li_, ri_, sr_, out); }
}

// ---- Kernel 2: per node, diag = sum over 32 outgoing directed edges of F^T F ----
template<bool F32M>
__device__ __forceinline__ void diag_body(int u, const void* maps, float* __restrict__ out) {
    float acc[16];
#pragma unroll
    for (int i = 0; i < 16; ++i) acc[i] = 0.f;
#pragma unroll 4
    for (int s = 1; s <= DG; ++s) {             // e = u*16 + s-1 (src=u, dst=u+s)
        float F[16]; load_map<F32M>(maps, (size_t)u*DG + (s-1), F);
#pragma unroll
        for (int x = 0; x < 4; ++x)
#pragma unroll
            for (int y = 0; y < 4; ++y)
                acc[x*4+y] += F[x]*F[y] + F[4+x]*F[4+y] + F[8+x]*F[8+y] + F[12+x]*F[12+y];
    }
#pragma unroll 4
    for (int s = 1; s <= DG; ++s) {             // e = M + ((u-s)%N)*16 + s-1 (src=u)
        int w = u - s; if (w < 0) w += NN;
        float F[16]; load_map<F32M>(maps, (size_t)EM + (size_t)w*DG + (s-1), F);
#pragma unroll
        for (int x = 0; x < 4; ++x)
#pragma unroll
            for (int y = 0; y < 4; ++y)
                acc[x*4+y] += F[x]*F[y] + F[4+x]*F[4+y] + F[8+x]*F[8+y] + F[12+x]*F[12+y];
    }
    int r = brank(u, u);
    float* wd = out + OFF_W + (size_t)u*528 + r*4;
#pragma unroll
    for (int x = 0; x < 4; ++x)
        *((float4*)(wd + x*132)) = make_float4(acc[x*4], acc[x*4+1], acc[x*4+2], acc[x*4+3]);
}
__global__ void k_diag(const void* __restrict__ maps, float* __restrict__ out,
                       const int* __restrict__ fl) {
    int u = blockIdx.x * 256 + threadIdx.x;
    if (u >= NN) return;
    if (fl[1]) diag_body<true >(u, maps, out);
    else       diag_body<false>(u, maps, out);
}

// ---- Kernel 3: edge_index rows/cols, pure function of output position ----
__global__ void k_idx(float* __restrict__ out) {
    int t = blockIdx.x * 256 + threadIdx.x;      // one thread = 4 consecutive entries
    if (t >= NIDX) return;
    int u = t / 132;
    int q = t - u * 132;
    int i = q / 33;
    int bb = q - i * 33;                         // sorted block index 0..32
    int a0 = u - DG; if (a0 < 0) a0 += NN;
    int v;
    if (a0 <= NN - 33) v = a0 + bb;
    else { int k = a0 + 33 - NN; v = (bb < k) ? bb : a0 + (bb - k); }
    float rf = (float)(u * 4 + i);
    float c0 = (float)(v * 4);
    ((float4*)out)[t]              = make_float4(rf, rf, rf, rf);
    ((float4*)(out + OFF_COLS))[t] = make_float4(c0, c0 + 1.f, c0 + 2.f, c0 + 3.f);
}

extern "C" void kernel_launch(void* const* d_in, const int* in_sizes, int n_in,
                              void* d_out, int out_size, void* d_ws, size_t ws_size,
                              hipStream_t stream) {
    const void* maps = d_in[0];
    const void* li   = d_in[1];
    const void* ri   = d_in[2];
    const void* sr   = d_in[3];
    float* out = (float*)d_out;
    int* flags = (int*)d_ws;
    k_detect<<<1, 64, 0, stream>>>((const u32*)maps, (const u32*)li, flags);
    k_edges<<<(EM + 255) / 256, 256, 0, stream>>>(maps, li, ri, sr, out, flags);
    k_diag<<<(NN + 255) / 256, 256, 0, stream>>>(maps, out, flags);
    k_idx<<<(NIDX + 255) / 256, 256, 0, stream>>>(out);
}

// Round 4
// 124.393 us; speedup vs baseline: 1.2235x; 1.2235x over previous
//
#include <hip/hip_runtime.h>

// Ring-lattice sheaf Laplacian builder: N=50000 nodes, strides 1..16, d=4.
// d_out is FLOAT32, outputs concatenated flat (element offsets):
//   edge_index rows [0, 26.4M) | cols [26.4M, 52.8M)
//   weights         [52.8M, 79.2M)
//   saved_tril_maps [79.2M, 92.0M)
#define NN 50000
#define DG 16
#define EM 800000
#define OFF_COLS 26400000
#define OFF_W    52800000
#define OFF_TRIL 79200000
#define NIDX 6600000

#define NB_E 3125      // ceil(EM/256)
#define NB_D 196       // ceil(NN/256)
#define NB_I 25782     // ceil(NIDX/256)

typedef unsigned int  u32;
typedef long long ll64;
typedef float f4v __attribute__((ext_vector_type(4)));

__device__ __forceinline__ void nt_store4(float* p, float a, float b, float c, float d) {
    f4v v = {a, b, c, d};
    __builtin_nontemporal_store(v, (f4v*)p);
}

// ---- bf16 unpack (maps may be bf16-packed) ----
__device__ __forceinline__ void unpack8(uint4 v, float* f) {
    f[0] = __uint_as_float(v.x << 16); f[1] = __uint_as_float(v.x & 0xffff0000u);
    f[2] = __uint_as_float(v.y << 16); f[3] = __uint_as_float(v.y & 0xffff0000u);
    f[4] = __uint_as_float(v.z << 16); f[5] = __uint_as_float(v.z & 0xffff0000u);
    f[6] = __uint_as_float(v.w << 16); f[7] = __uint_as_float(v.w & 0xffff0000u);
}

// rank of node v within sorted({u} U {u +- s mod N, s=1..16}); 33 distinct values.
__device__ __forceinline__ int brank(int u, int v) {
    int a0 = u - DG; if (a0 < 0) a0 += NN;
    if (a0 <= NN - 33) return v - a0;          // contiguous [a0, a0+32]
    int k = a0 + 33 - NN;                      // wrapped values 0..k-1 sort first
    return (v < k) ? v : k + (v - a0);
}

// ---- dtype-flexible input loads ----
template<bool F32M>
__device__ __forceinline__ void load_map(const void* maps, size_t e, float* F) {
    if (F32M) {
        const float4* p = (const float4*)maps;
        float4 a = p[e*4+0], b = p[e*4+1], c = p[e*4+2], d = p[e*4+3];
        F[0]=a.x; F[1]=a.y; F[2]=a.z; F[3]=a.w;
        F[4]=b.x; F[5]=b.y; F[6]=b.z; F[7]=b.w;
        F[8]=c.x; F[9]=c.y; F[10]=c.z; F[11]=c.w;
        F[12]=d.x; F[13]=d.y; F[14]=d.z; F[15]=d.w;
    } else {
        const uint4* p = (const uint4*)maps;
        unpack8(p[e*2], F); unpack8(p[e*2+1], F + 8);
    }
}
template<bool I64>
__device__ __forceinline__ int ld_idx(const void* p, size_t i) {
    return I64 ? (int)((const ll64*)p)[i] : ((const int*)p)[i];
}

// ---- inline detection (uniform scalar loads; ~free) ----
__device__ __forceinline__ void detect(const u32* __restrict__ mw,
                                       const u32* __restrict__ lw,
                                       int& i64, int& f32m) {
    u32 odd = lw[1] | lw[3] | lw[5] | lw[7];      // int64 => high words all zero
    i64 = (odd == 0u) ? 1 : 0;
    int sane = 0;
#pragma unroll
    for (int i = 0; i < 32; ++i) {                // low half as bf16: sane exponent?
        u32 ex = (mw[i] >> 7) & 0xFFu;
        sane += (ex >= 0x70u && ex <= 0x87u) ? 1 : 0;
    }
    f32m = (sane < 16) ? 1 : 0;                   // few sane => raw f32 bits
}

// ---- edges: per tril edge, T = -L^T R -> tril + block(a,b) + block(b,a) ----
template<bool I64, bool F32M>
__device__ __forceinline__ void edges_body(int m, const void* maps, const void* li_,
                                           const void* ri_, const void* sr_,
                                           float* __restrict__ out) {
    int li = ld_idx<I64>(li_, m), ri = ld_idx<I64>(ri_, m);
    int a  = ld_idx<I64>(sr_, li), b = ld_idx<I64>(sr_, ri);   // a = src > dst = b
    float L[16], R[16];
    load_map<F32M>(maps, (size_t)li, L);
    load_map<F32M>(maps, (size_t)ri, R);
    float T[16];
#pragma unroll
    for (int x = 0; x < 4; ++x)
#pragma unroll
        for (int y = 0; y < 4; ++y)
            T[x*4+y] = -(L[x]*R[y] + L[4+x]*R[4+y] + L[8+x]*R[8+y] + L[12+x]*R[12+y]);
    // saved_tril_maps[m] (contiguous, streaming -> nt)
    float* tp = out + OFF_TRIL + (size_t)m * 16;
    nt_store4(tp + 0,  T[0],  T[1],  T[2],  T[3]);
    nt_store4(tp + 4,  T[4],  T[5],  T[6],  T[7]);
    nt_store4(tp + 8,  T[8],  T[9],  T[10], T[11]);
    nt_store4(tp + 12, T[12], T[13], T[14], T[15]);
    // block (a,b): T[x][y] at global row a*4+x, col slot brank(a,b)*4+y
    int ra = brank(a, b);
    float* wa = out + OFF_W + (size_t)a*528 + ra*4;
#pragma unroll
    for (int x = 0; x < 4; ++x)
        *((float4*)(wa + x*132)) = make_float4(T[x*4], T[x*4+1], T[x*4+2], T[x*4+3]);
    // block (b,a) = T^T
    int rb = brank(b, a);
    float* wb = out + OFF_W + (size_t)b*528 + rb*4;
#pragma unroll
    for (int p = 0; p < 4; ++p)
        *((float4*)(wb + p*132)) = make_float4(T[p], T[4+p], T[8+p], T[12+p]);
}

// ---- diag: per node, sum over 32 outgoing directed edges of F^T F ----
template<bool F32M>
__device__ __forceinline__ void diag_body(int u, const void* maps, float* __restrict__ out) {
    float acc[16];
#pragma unroll
    for (int i = 0; i < 16; ++i) acc[i] = 0.f;
#pragma unroll 4
    for (int s = 1; s <= DG; ++s) {             // e = u*16 + s-1 (src=u, dst=u+s)
        float F[16]; load_map<F32M>(maps, (size_t)u*DG + (s-1), F);
#pragma unroll
        for (int x = 0; x < 4; ++x)
#pragma unroll
            for (int y = 0; y < 4; ++y)
                acc[x*4+y] += F[x]*F[y] + F[4+x]*F[4+y] + F[8+x]*F[8+y] + F[12+x]*F[12+y];
    }
#pragma unroll 4
    for (int s = 1; s <= DG; ++s) {             // e = M + ((u-s)%N)*16 + s-1 (src=u)
        int w = u - s; if (w < 0) w += NN;
        float F[16]; load_map<F32M>(maps, (size_t)EM + (size_t)w*DG + (s-1), F);
#pragma unroll
        for (int x = 0; x < 4; ++x)
#pragma unroll
            for (int y = 0; y < 4; ++y)
                acc[x*4+y] += F[x]*F[y] + F[4+x]*F[4+y] + F[8+x]*F[8+y] + F[12+x]*F[12+y];
    }
    int r = brank(u, u);
    float* wd = out + OFF_W + (size_t)u*528 + r*4;
#pragma unroll
    for (int x = 0; x < 4; ++x)
        *((float4*)(wd + x*132)) = make_float4(acc[x*4], acc[x*4+1], acc[x*4+2], acc[x*4+3]);
}

// ---- idx: edge_index rows/cols, pure function of output position ----
__device__ __forceinline__ void idx_body(int t, float* __restrict__ out) {
    int u = t / 132;
    int q = t - u * 132;
    int i = q / 33;
    int bb = q - i * 33;                         // sorted block index 0..32
    int a0 = u - DG; if (a0 < 0) a0 += NN;
    int v;
    if (a0 <= NN - 33) v = a0 + bb;
    else { int k = a0 + 33 - NN; v = (bb < k) ? bb : a0 + (bb - k); }
    float rf = (float)(u * 4 + i);
    float c0 = (float)(v * 4);
    nt_store4(out + (size_t)t*4,            rf, rf,       rf,       rf);
    nt_store4(out + OFF_COLS + (size_t)t*4, c0, c0 + 1.f, c0 + 2.f, c0 + 3.f);
}

// ---- fused kernel: blocks [0,NB_E) edges | [NB_E,NB_E+NB_D) diag | rest idx ----
__global__ void k_fused(const void* __restrict__ maps, const void* __restrict__ li_,
                        const void* __restrict__ ri_, const void* __restrict__ sr_,
                        float* __restrict__ out) {
    int blk = blockIdx.x;
    if (blk < NB_E) {
        int m = blk * 256 + threadIdx.x;
        if (m >= EM) return;
        int i6, f3;
        detect((const u32*)maps, (const u32*)li_, i6, f3);
        if (i6) { if (f3) edges_body<true ,true >(m, maps, li_, ri_, sr_, out);
                  else    edges_body<true ,false>(m, maps, li_, ri_, sr_, out); }
        else    { if (f3) edges_body<false,true >(m, maps, li_, ri_, sr_, out);
                  else    edges_body<false,false>(m, maps, li_, ri_, sr_, out); }
    } else if (blk < NB_E + NB_D) {
        int u = (blk - NB_E) * 256 + threadIdx.x;
        if (u >= NN) return;
        int i6, f3;
        detect((const u32*)maps, (const u32*)li_, i6, f3);
        if (f3) diag_body<true >(u, maps, out);
        else    diag_body<false>(u, maps, out);
    } else {
        int t = (blk - NB_E - NB_D) * 256 + threadIdx.x;
        if (t >= NIDX) return;
        idx_body(t, out);
    }
}

extern "C" void kernel_launch(void* const* d_in, const int* in_sizes, int n_in,
                              void* d_out, int out_size, void* d_ws, size_t ws_size,
                              hipStream_t stream) {
    const void* maps = d_in[0];
    const void* li   = d_in[1];
    const void* ri   = d_in[2];
    const void* sr   = d_in[3];
    float* out = (float*)d_out;
    k_fused<<<NB_E + NB_D + NB_I, 256, 0, stream>>>(maps, li, ri, sr, out);
}